// Round 1
// baseline (308.211 us; speedup 1.0000x reference)
//
#include <hip/hip_runtime.h>

typedef float v4 __attribute__((ext_vector_type(4)));

#define TWO_PI_256 0.024543692606170259f  // 2*pi/256

// Geometry: B=16, Ci=32, Co=32, H=256, W=256, modes M=16.
// K1: w-DFT   x[bc*H + h][256] -> F[row][32]   (o=2kx: Re, o=2kx+1: Im)
// K2: h-DFT   F -> X[bc][ky][kx] complex
// K3: mix     Y[b][co][ky][kx] = sum_ci X[b][ci] * Wc[ci][co]
// K4: inverse G[h][kx] = sum_ky Y e^{+i ky h th}; out[h][w] = (Gr0 + 2*sum_kx Re(G e^{+i kx w th}))/65536

__global__ __launch_bounds__(256) void k1_dftw(const float* __restrict__ x,
                                               float* __restrict__ F) {
  __shared__ float2 tbl[256];
  __shared__ float T[32][264];   // [o][k], stride 264 floats (2-way-free banks)
  __shared__ float Xs[32][132];  // [k][row], stride 132 floats (16B aligned rows)
  const int tid = threadIdx.x;
  {
    float sv, cv;
    sincosf((float)tid * TWO_PI_256, &sv, &cv);
    tbl[tid] = make_float2(cv, sv);
  }
  __syncthreads();
#pragma unroll
  for (int kx = 0; kx < 16; ++kx) {
    const float2 v = tbl[(kx * tid) & 255];
    T[2 * kx][tid] = v.x;       // cos
    T[2 * kx + 1][tid] = -v.y;  // -sin  (forward DFT)
  }
  const int cg = tid & 7;       // col group: o0 = 4*cg
  const int rg = tid >> 3;      // row group: r0 = 4*rg (32 groups -> 128 rows)
  const int o0 = cg * 4;
  const int r0 = rg * 4;
  const long rblk = (long)blockIdx.x * 128;
  float acc[4][4] = {};
  for (int kc = 0; kc < 256; kc += 32) {
    __syncthreads();
#pragma unroll
    for (int p = 0; p < 4; ++p) {
      const int row = (tid >> 3) + p * 32;
      const int k4 = (tid & 7) * 4;
      const v4 v = *(const v4*)&x[(rblk + row) * 256 + kc + k4];
      Xs[k4 + 0][row] = v[0];
      Xs[k4 + 1][row] = v[1];
      Xs[k4 + 2][row] = v[2];
      Xs[k4 + 3][row] = v[3];
    }
    __syncthreads();
#pragma unroll
    for (int k = 0; k < 32; k += 4) {
      v4 xv[4], tv[4];
#pragma unroll
      for (int i = 0; i < 4; ++i) xv[i] = *(const v4*)&Xs[k + i][r0];
#pragma unroll
      for (int c = 0; c < 4; ++c) tv[c] = *(const v4*)&T[o0 + c][kc + k];
#pragma unroll
      for (int i = 0; i < 4; ++i)
#pragma unroll
        for (int r = 0; r < 4; ++r)
#pragma unroll
          for (int c = 0; c < 4; ++c) acc[r][c] += xv[i][r] * tv[c][i];
    }
  }
#pragma unroll
  for (int r = 0; r < 4; ++r) {
    v4 o;
#pragma unroll
    for (int c = 0; c < 4; ++c) o[c] = acc[r][c];
    *(v4*)&F[(rblk + r0 + r) * 32 + o0] = o;
  }
}

__global__ __launch_bounds__(256) void k2_dfth(const float* __restrict__ F,
                                               float* __restrict__ X) {
  __shared__ float2 tbl[256];
  __shared__ float Fs[64][36];  // [h][o], stride 36 (16B aligned rows)
  const int tid = threadIdx.x;
  const int bc = blockIdx.x;
  {
    float sv, cv;
    sincosf((float)tid * TWO_PI_256, &sv, &cv);
    tbl[tid] = make_float2(cv, sv);
  }
  const int kx = tid & 15;
  const int ky = tid >> 4;
  float xr = 0.f, xi = 0.f;
  const float* Fb = F + (long)bc * 8192;
  for (int hc = 0; hc < 256; hc += 64) {
    __syncthreads();
#pragma unroll
    for (int p = 0; p < 2; ++p) {
      const int h = (tid >> 3) + p * 32;
      const int j = (tid & 7) * 4;
      *(v4*)&Fs[h][j] = *(const v4*)&Fb[(hc + h) * 32 + j];
    }
    __syncthreads();
#pragma unroll 8
    for (int hl = 0; hl < 64; ++hl) {
      const int h = hc + hl;
      const float2 f = *(const float2*)&Fs[hl][2 * kx];
      const float2 w = tbl[(ky * h) & 255];  // e^{-i th}: (cos, sin)
      xr += f.x * w.x + f.y * w.y;
      xi += f.y * w.x - f.x * w.y;
    }
  }
  *(float2*)&X[((long)bc * 256 + tid) * 2] = make_float2(xr, xi);
}

__global__ __launch_bounds__(256) void k3_mix(const float* __restrict__ X,
                                              const float* __restrict__ Wt,
                                              float* __restrict__ Y) {
  const int t = threadIdx.x;        // mode = ky*16 + kx
  const int co = blockIdx.x;
  const int b = blockIdx.y;
  float yr = 0.f, yi = 0.f;
#pragma unroll 4
  for (int ci = 0; ci < 32; ++ci) {
    const float2 xv = *(const float2*)&X[((long)(b * 32 + ci) * 256 + t) * 2];
    const float2 wv = *(const float2*)&Wt[((long)(ci * 32 + co) * 256 + t) * 2];
    yr += xv.x * wv.x - xv.y * wv.y;
    yi += xv.x * wv.y + xv.y * wv.x;
  }
  *(float2*)&Y[((long)(b * 32 + co) * 256 + t) * 2] = make_float2(yr, yi);
}

__global__ __launch_bounds__(256) void k4_inv(const float* __restrict__ Y,
                                              float* __restrict__ out) {
  __shared__ float2 tbl[256];
  __shared__ float2 Ys[256];
  __shared__ float G[256][36];  // [h][2*kx(+1)], 144B rows (16B aligned)
  const int tid = threadIdx.x;
  const int co = blockIdx.x;
  const int b = blockIdx.y;
  {
    float sv, cv;
    sincosf((float)tid * TWO_PI_256, &sv, &cv);
    tbl[tid] = make_float2(cv, sv);
  }
  Ys[tid] = *(const float2*)&Y[((long)(b * 32 + co) * 256 + tid) * 2];
  __syncthreads();
  {  // phase 1: thread = h; G[h][kx] = sum_ky Y[ky][kx] * e^{+i ky h th}
    float gr[16] = {}, gi[16] = {};
#pragma unroll 4
    for (int ky = 0; ky < 16; ++ky) {
      const float2 w = tbl[(ky * tid) & 255];
#pragma unroll
      for (int kx = 0; kx < 16; ++kx) {
        const float2 yv = Ys[ky * 16 + kx];
        gr[kx] += yv.x * w.x - yv.y * w.y;
        gi[kx] += yv.x * w.y + yv.y * w.x;
      }
    }
#pragma unroll
    for (int kx = 0; kx < 16; ++kx)
      *(float2*)&G[tid][2 * kx] = make_float2(gr[kx], gi[kx]);
  }
  __syncthreads();
  // phase 2: thread = (w-slot s, h-parity hh); fold w <-> 256-w
  const int s = tid & 127;
  const int hh = tid >> 7;
  float cs[16], sn[16];
#pragma unroll
  for (int kx = 1; kx < 16; ++kx) {
    const float2 w = tbl[(kx * s) & 255];
    cs[kx] = 2.f * w.x;
    sn[kx] = 2.f * w.y;
  }
  const float inv = 1.f / 65536.f;
  float* __restrict__ ob = out + (long)(b * 32 + co) * 65536;
  for (int h = hh; h < 256; h += 2) {
    float gr[16], gi[16];
#pragma unroll
    for (int j = 0; j < 8; ++j) {
      const v4 q = *(const v4*)&G[h][4 * j];
      gr[2 * j] = q[0];
      gi[2 * j] = q[1];
      gr[2 * j + 1] = q[2];
      gi[2 * j + 1] = q[3];
    }
    float a = gr[0];
    float bs = 0.f;
#pragma unroll
    for (int kx = 1; kx < 16; ++kx) {
      a += gr[kx] * cs[kx];
      bs += gi[kx] * sn[kx];
    }
    if (s == 0) {
      // w=0 (cs=2, sn=0 -> a is correct) and w=128 (cos = (-1)^kx, sin = 0)
      float a128 = gr[0];
#pragma unroll
      for (int kx = 1; kx < 16; ++kx)
        a128 += (kx & 1) ? -2.f * gr[kx] : 2.f * gr[kx];
      ob[h * 256] = a * inv;
      ob[h * 256 + 128] = a128 * inv;
    } else {
      ob[h * 256 + s] = (a - bs) * inv;
      ob[h * 256 + 256 - s] = (a + bs) * inv;
    }
  }
}

extern "C" void kernel_launch(void* const* d_in, const int* in_sizes, int n_in,
                              void* d_out, int out_size, void* d_ws, size_t ws_size,
                              hipStream_t stream) {
  const float* x = (const float*)d_in[0];   // [16][32][256][256]
  const float* wt = (const float*)d_in[1];  // [32][32][16][16][2]
  float* out = (float*)d_out;               // [16][32][256][256]
  float* F = (float*)d_ws;                  // 131072*32 floats = 16.78 MB
  float* X = F + 4194304;                   // 512*256*2 floats = 1 MB
  float* Yv = X + 262144;                   // 512*256*2 floats = 1 MB
  k1_dftw<<<1024, 256, 0, stream>>>(x, F);
  k2_dfth<<<512, 256, 0, stream>>>(F, X);
  k3_mix<<<dim3(32, 16), 256, 0, stream>>>(X, wt, Yv);
  k4_inv<<<dim3(32, 16), 256, 0, stream>>>(Yv, out);
}

// Round 2
// 297.267 us; speedup vs baseline: 1.0368x; 1.0368x over previous
//
#include <hip/hip_runtime.h>

typedef float v4 __attribute__((ext_vector_type(4)));

#define TWO_PI_256 0.024543692606170259f  // 2*pi/256

// Geometry: B=16, Ci=32, Co=32, H=256, W=256, modes M=16.
// k0: trig table Tg[k][o] : o=2kx -> cos(2pi kx k/256), o=2kx+1 -> -sin(...)
// K1: w-DFT   x[bc*H + h][256] -> F[row][32]   (o=2kx: Re, o=2kx+1: Im)
// K2: h-DFT   F -> X[bc][ky][kx] complex
// K3: mix     Y[b][co][ky][kx] = sum_ci X[b][ci] * Wc[ci][co]
// K4: inverse G[h][kx] = sum_ky Y e^{+i ky h th}; out[h][w] = (Gr0 + 2*sum_kx Re(G e^{+i kx w th}))/65536

__global__ __launch_bounds__(256) void k0_trig(float* __restrict__ Tg) {
  const int k = threadIdx.x;
#pragma unroll
  for (int kx = 0; kx < 16; ++kx) {
    float sv, cv;
    sincosf((float)((kx * k) & 255) * TWO_PI_256, &sv, &cv);
    Tg[k * 32 + 2 * kx] = cv;
    Tg[k * 32 + 2 * kx + 1] = -sv;
  }
}

typedef __attribute__((address_space(1))) const unsigned int gas_u32;
typedef __attribute__((address_space(3))) unsigned int las_u32;

__global__ __launch_bounds__(256, 4) void k1_dftw(const float* __restrict__ x,
                                                  const float* __restrict__ Tg,
                                                  float* __restrict__ F) {
  __shared__ float Ts[32][32];   // [k][o] — lane-varying o contiguous: conflict-free b128
  __shared__ float Xs[32][132];  // [k][row] — lane-varying row contiguous: conflict-free b128
  const int tid = threadIdx.x;
  const int cg = tid & 7;   // col group: o0 = 4*cg
  const int rg = tid >> 3;  // row group: r0 = 4*rg (32 groups -> 128 rows)
  const int o0 = cg * 4;
  const int r0 = rg * 4;
  const long rblk = (long)blockIdx.x * 128;
  float acc[4][4] = {};
  for (int kc = 0; kc < 256; kc += 32) {
    __syncthreads();
    // stage T chunk [kc..kc+32)[32] = 4KB, lane-linear: lds <- wave base + lane*16
    __builtin_amdgcn_global_load_lds(
        (gas_u32*)(Tg + kc * 32 + tid * 4),
        (las_u32*)((unsigned int*)&Ts[0][0] + (tid >> 6) * 256), 16, 0, 0);
    // stage x chunk transposed
#pragma unroll
    for (int p = 0; p < 4; ++p) {
      const int row = (tid >> 3) + p * 32;
      const int k4 = (tid & 7) * 4;
      const v4 v = *(const v4*)&x[(rblk + row) * 256 + kc + k4];
      Xs[k4 + 0][row] = v[0];
      Xs[k4 + 1][row] = v[1];
      Xs[k4 + 2][row] = v[2];
      Xs[k4 + 3][row] = v[3];
    }
    __syncthreads();
#pragma unroll
    for (int k = 0; k < 32; k += 4) {
      v4 xv[4], tv[4];
#pragma unroll
      for (int i = 0; i < 4; ++i) xv[i] = *(const v4*)&Xs[k + i][r0];
#pragma unroll
      for (int i = 0; i < 4; ++i) tv[i] = *(const v4*)&Ts[k + i][o0];
#pragma unroll
      for (int i = 0; i < 4; ++i)
#pragma unroll
        for (int r = 0; r < 4; ++r)
#pragma unroll
          for (int c = 0; c < 4; ++c) acc[r][c] += xv[i][r] * tv[i][c];
    }
  }
#pragma unroll
  for (int r = 0; r < 4; ++r) {
    v4 o;
#pragma unroll
    for (int c = 0; c < 4; ++c) o[c] = acc[r][c];
    *(v4*)&F[(rblk + r0 + r) * 32 + o0] = o;
  }
}

__global__ __launch_bounds__(256) void k2_dfth(const float* __restrict__ F,
                                               float* __restrict__ X) {
  __shared__ float2 tbl[256];
  __shared__ float Fs[64][36];  // [h][o], stride 36 (16B aligned rows)
  const int tid = threadIdx.x;
  const int bc = blockIdx.x;
  {
    float sv, cv;
    sincosf((float)tid * TWO_PI_256, &sv, &cv);
    tbl[tid] = make_float2(cv, sv);
  }
  const int kx = tid & 15;
  const int ky = tid >> 4;
  float xr = 0.f, xi = 0.f;
  const float* Fb = F + (long)bc * 8192;
  for (int hc = 0; hc < 256; hc += 64) {
    __syncthreads();
#pragma unroll
    for (int p = 0; p < 2; ++p) {
      const int h = (tid >> 3) + p * 32;
      const int j = (tid & 7) * 4;
      *(v4*)&Fs[h][j] = *(const v4*)&Fb[(hc + h) * 32 + j];
    }
    __syncthreads();
#pragma unroll 8
    for (int hl = 0; hl < 64; ++hl) {
      const int h = hc + hl;
      const float2 f = *(const float2*)&Fs[hl][2 * kx];
      const float2 w = tbl[(ky * h) & 255];  // e^{-i th}: (cos, sin)
      xr += f.x * w.x + f.y * w.y;
      xi += f.y * w.x - f.x * w.y;
    }
  }
  *(float2*)&X[((long)bc * 256 + tid) * 2] = make_float2(xr, xi);
}

__global__ __launch_bounds__(256) void k3_mix(const float* __restrict__ X,
                                              const float* __restrict__ Wt,
                                              float* __restrict__ Y) {
  const int t = threadIdx.x;        // mode = ky*16 + kx
  const int co = blockIdx.x;
  const int b = blockIdx.y;
  float yr = 0.f, yi = 0.f;
#pragma unroll 4
  for (int ci = 0; ci < 32; ++ci) {
    const float2 xv = *(const float2*)&X[((long)(b * 32 + ci) * 256 + t) * 2];
    const float2 wv = *(const float2*)&Wt[((long)(ci * 32 + co) * 256 + t) * 2];
    yr += xv.x * wv.x - xv.y * wv.y;
    yi += xv.x * wv.y + xv.y * wv.x;
  }
  *(float2*)&Y[((long)(b * 32 + co) * 256 + t) * 2] = make_float2(yr, yi);
}

__global__ __launch_bounds__(256) void k4_inv(const float* __restrict__ Y,
                                              float* __restrict__ out) {
  __shared__ float2 tbl[256];
  __shared__ float2 Ys[256];
  __shared__ float G[256][36];  // [h][2*kx(+1)], 144B rows (16B aligned)
  const int tid = threadIdx.x;
  const int co = blockIdx.x;
  const int b = blockIdx.y;
  {
    float sv, cv;
    sincosf((float)tid * TWO_PI_256, &sv, &cv);
    tbl[tid] = make_float2(cv, sv);
  }
  Ys[tid] = *(const float2*)&Y[((long)(b * 32 + co) * 256 + tid) * 2];
  __syncthreads();
  {  // phase 1: thread = h; G[h][kx] = sum_ky Y[ky][kx] * e^{+i ky h th}
    float gr[16] = {}, gi[16] = {};
#pragma unroll 4
    for (int ky = 0; ky < 16; ++ky) {
      const float2 w = tbl[(ky * tid) & 255];
#pragma unroll
      for (int kx = 0; kx < 16; ++kx) {
        const float2 yv = Ys[ky * 16 + kx];
        gr[kx] += yv.x * w.x - yv.y * w.y;
        gi[kx] += yv.x * w.y + yv.y * w.x;
      }
    }
#pragma unroll
    for (int kx = 0; kx < 16; ++kx)
      *(float2*)&G[tid][2 * kx] = make_float2(gr[kx], gi[kx]);
  }
  __syncthreads();
  // phase 2: thread = (w-slot s, h-parity hh); fold w <-> 256-w
  const int s = tid & 127;
  const int hh = tid >> 7;
  float cs[16], sn[16];
#pragma unroll
  for (int kx = 1; kx < 16; ++kx) {
    const float2 w = tbl[(kx * s) & 255];
    cs[kx] = 2.f * w.x;
    sn[kx] = 2.f * w.y;
  }
  const float inv = 1.f / 65536.f;
  float* __restrict__ ob = out + (long)(b * 32 + co) * 65536;
  for (int h = hh; h < 256; h += 2) {
    float gr[16], gi[16];
#pragma unroll
    for (int j = 0; j < 8; ++j) {
      const v4 q = *(const v4*)&G[h][4 * j];
      gr[2 * j] = q[0];
      gi[2 * j] = q[1];
      gr[2 * j + 1] = q[2];
      gi[2 * j + 1] = q[3];
    }
    float a = gr[0];
    float bs = 0.f;
#pragma unroll
    for (int kx = 1; kx < 16; ++kx) {
      a += gr[kx] * cs[kx];
      bs += gi[kx] * sn[kx];
    }
    if (s == 0) {
      // w=0 (cs=2, sn=0 -> a is correct) and w=128 (cos = (-1)^kx, sin = 0)
      float a128 = gr[0];
#pragma unroll
      for (int kx = 1; kx < 16; ++kx)
        a128 += (kx & 1) ? -2.f * gr[kx] : 2.f * gr[kx];
      ob[h * 256] = a * inv;
      ob[h * 256 + 128] = a128 * inv;
    } else {
      ob[h * 256 + s] = (a - bs) * inv;
      ob[h * 256 + 256 - s] = (a + bs) * inv;
    }
  }
}

extern "C" void kernel_launch(void* const* d_in, const int* in_sizes, int n_in,
                              void* d_out, int out_size, void* d_ws, size_t ws_size,
                              hipStream_t stream) {
  const float* x = (const float*)d_in[0];   // [16][32][256][256]
  const float* wt = (const float*)d_in[1];  // [32][32][16][16][2]
  float* out = (float*)d_out;               // [16][32][256][256]
  float* F = (float*)d_ws;                  // 131072*32 floats = 16.78 MB
  float* X = F + 4194304;                   // 512*256*2 floats = 1 MB
  float* Yv = X + 262144;                   // 512*256*2 floats = 1 MB
  float* Tg = Yv + 262144;                  // 256*32 floats = 32 KB
  k0_trig<<<1, 256, 0, stream>>>(Tg);
  k1_dftw<<<1024, 256, 0, stream>>>(x, Tg, F);
  k2_dfth<<<512, 256, 0, stream>>>(F, X);
  k3_mix<<<dim3(32, 16), 256, 0, stream>>>(X, wt, Yv);
  k4_inv<<<dim3(32, 16), 256, 0, stream>>>(Yv, out);
}

// Round 3
// 296.034 us; speedup vs baseline: 1.0411x; 1.0042x over previous
//
#include <hip/hip_runtime.h>

typedef float v4 __attribute__((ext_vector_type(4)));
typedef float f32x4 __attribute__((ext_vector_type(4)));
typedef short bf16x8 __attribute__((ext_vector_type(8)));

#define TWO_PI_256 0.024543692606170259f  // 2*pi/256

// Geometry: B=16, Ci=32, Co=32, H=256, W=256, modes M=16.
// k0: trig table (bf16 split) Th/Tl[o][k], o=2kx: cos(2pi kx k/256), o=2kx+1: -sin
// K1: w-DFT  x[bc*H + h][256] -> F[row][32]  via split-bf16 MFMA (hi*hi+lo*hi+hi*lo)
// K2: h-DFT  F -> X[bc][ky][kx] complex
// K3: mix    Y[b][co][ky][kx] = sum_ci X[b][ci] * Wc[ci][co]
// K4: inverse G[h][kx] = sum_ky Y e^{+i ky h th}; out[h][w] = (Gr0 + 2*sum_kx Re(G e^{+i kx w th}))/65536

__device__ __forceinline__ unsigned short f2bf(float f) {
  const unsigned int u = __float_as_uint(f);
  return (unsigned short)((u + 0x7fffu + ((u >> 16) & 1u)) >> 16);  // RNE
}
__device__ __forceinline__ float bf2f(unsigned short h) {
  return __uint_as_float(((unsigned int)h) << 16);
}

__global__ __launch_bounds__(256) void k0_trig(unsigned short* __restrict__ Th,
                                               unsigned short* __restrict__ Tl) {
  const int k = threadIdx.x;
#pragma unroll
  for (int kx = 0; kx < 16; ++kx) {
    float sv, cv;
    sincosf((float)((kx * k) & 255) * TWO_PI_256, &sv, &cv);
    const float vals[2] = {cv, -sv};
#pragma unroll
    for (int p = 0; p < 2; ++p) {
      const int o = 2 * kx + p;
      const unsigned short hi = f2bf(vals[p]);
      Th[o * 256 + k] = hi;
      Tl[o * 256 + k] = f2bf(vals[p] - bf2f(hi));
    }
  }
}

typedef __attribute__((address_space(1))) const unsigned int gas_u32;
typedef __attribute__((address_space(3))) unsigned int las_u32;

__global__ __launch_bounds__(256) void k1_dftw(const float* __restrict__ x,
                                               const unsigned short* __restrict__ Th,
                                               const unsigned short* __restrict__ Tl,
                                               float* __restrict__ F) {
  __shared__ float Xs[128 * 32];                          // [row][k] fp32, unpadded (glb_load_lds)
  __shared__ __align__(16) unsigned short Ts[2][32 * 264];  // [fmt][o][k] bf16, padded rows
  const int tid = threadIdx.x;
  const int lane = tid & 63;
  const int w = tid >> 6;
  const long rblk = (long)blockIdx.x * 128;
  // stage T once: thread -> (o = tid>>3, k-block = (tid&7)*32)
  {
    const int o = tid >> 3, kb = (tid & 7) * 32;
#pragma unroll
    for (int f = 0; f < 2; ++f) {
      const unsigned short* src = (f ? Tl : Th) + o * 256 + kb;
      unsigned short* dst = &Ts[f][o * 264 + kb];
#pragma unroll
      for (int j = 0; j < 32; j += 8)
        *(bf16x8*)(dst + j) = *(const bf16x8*)(src + j);
    }
  }
  const int q = lane >> 4;    // 0..3
  const int n16 = lane & 15;  // 0..15
  f32x4 acc[2][2] = {};
  for (int kc = 0; kc < 256; kc += 32) {
    __syncthreads();
    // stage Xs: wave w covers rows [w*32, w*32+32), 4 x 1KB lane-linear DMA
#pragma unroll
    for (int i = 0; i < 4; ++i) {
      const int r0 = w * 32 + i * 8;
      __builtin_amdgcn_global_load_lds(
          (gas_u32*)(x + (rblk + r0 + (lane >> 3)) * 256 + kc + (lane & 7) * 4),
          (las_u32*)((unsigned int*)Xs + r0 * 32), 16, 0, 0);
    }
    __syncthreads();
    // B fragments: B[k][n], n = lane&15 -> o, k = q*8+j (contiguous bf16)
    bf16x8 bh[2], bl[2];
#pragma unroll
    for (int nt = 0; nt < 2; ++nt) {
      const int o = nt * 16 + n16;
      bh[nt] = *(const bf16x8*)&Ts[0][o * 264 + kc + q * 8];
      bl[nt] = *(const bf16x8*)&Ts[1][o * 264 + kc + q * 8];
    }
#pragma unroll
    for (int mt = 0; mt < 2; ++mt) {
      // A fragment: A[m][k], m = lane&15, k = q*8+j
      const int m = w * 32 + mt * 16 + n16;
      const float* ap = &Xs[m * 32 + q * 8];
      const v4 a0 = *(const v4*)ap;
      const v4 a1 = *(const v4*)(ap + 4);
      const float af[8] = {a0[0], a0[1], a0[2], a0[3], a1[0], a1[1], a1[2], a1[3]};
      bf16x8 ah, al;
#pragma unroll
      for (int j = 0; j < 8; ++j) {
        const unsigned short h = f2bf(af[j]);
        ah[j] = (short)h;
        al[j] = (short)f2bf(af[j] - bf2f(h));
      }
#pragma unroll
      for (int nt = 0; nt < 2; ++nt) {
        acc[mt][nt] = __builtin_amdgcn_mfma_f32_16x16x32_bf16(ah, bh[nt], acc[mt][nt], 0, 0, 0);
        acc[mt][nt] = __builtin_amdgcn_mfma_f32_16x16x32_bf16(al, bh[nt], acc[mt][nt], 0, 0, 0);
        acc[mt][nt] = __builtin_amdgcn_mfma_f32_16x16x32_bf16(ah, bl[nt], acc[mt][nt], 0, 0, 0);
      }
    }
  }
  // epilogue: row = w*32 + mt*16 + q*4 + reg, col = nt*16 + n16
#pragma unroll
  for (int mt = 0; mt < 2; ++mt)
#pragma unroll
    for (int nt = 0; nt < 2; ++nt)
#pragma unroll
      for (int r = 0; r < 4; ++r) {
        const long row = rblk + w * 32 + mt * 16 + q * 4 + r;
        F[row * 32 + nt * 16 + n16] = acc[mt][nt][r];
      }
}

__global__ __launch_bounds__(256) void k2_dfth(const float* __restrict__ F,
                                               float* __restrict__ X) {
  __shared__ float2 tbl[256];
  __shared__ float Fs[64][36];  // [h][o], stride 36 (16B aligned rows)
  const int tid = threadIdx.x;
  const int bc = blockIdx.x;
  {
    float sv, cv;
    sincosf((float)tid * TWO_PI_256, &sv, &cv);
    tbl[tid] = make_float2(cv, sv);
  }
  const int kx = tid & 15;
  const int ky = tid >> 4;
  float xr = 0.f, xi = 0.f;
  const float* Fb = F + (long)bc * 8192;
  for (int hc = 0; hc < 256; hc += 64) {
    __syncthreads();
#pragma unroll
    for (int p = 0; p < 2; ++p) {
      const int h = (tid >> 3) + p * 32;
      const int j = (tid & 7) * 4;
      *(v4*)&Fs[h][j] = *(const v4*)&Fb[(hc + h) * 32 + j];
    }
    __syncthreads();
#pragma unroll 8
    for (int hl = 0; hl < 64; ++hl) {
      const int h = hc + hl;
      const float2 f = *(const float2*)&Fs[hl][2 * kx];
      const float2 w = tbl[(ky * h) & 255];  // e^{-i th}: (cos, sin)
      xr += f.x * w.x + f.y * w.y;
      xi += f.y * w.x - f.x * w.y;
    }
  }
  *(float2*)&X[((long)bc * 256 + tid) * 2] = make_float2(xr, xi);
}

__global__ __launch_bounds__(256) void k3_mix(const float* __restrict__ X,
                                              const float* __restrict__ Wt,
                                              float* __restrict__ Y) {
  const int t = threadIdx.x;  // mode = ky*16 + kx
  const int co = blockIdx.x;
  const int b = blockIdx.y;
  float yr = 0.f, yi = 0.f;
#pragma unroll 4
  for (int ci = 0; ci < 32; ++ci) {
    const float2 xv = *(const float2*)&X[((long)(b * 32 + ci) * 256 + t) * 2];
    const float2 wv = *(const float2*)&Wt[((long)(ci * 32 + co) * 256 + t) * 2];
    yr += xv.x * wv.x - xv.y * wv.y;
    yi += xv.x * wv.y + xv.y * wv.x;
  }
  *(float2*)&Y[((long)(b * 32 + co) * 256 + t) * 2] = make_float2(yr, yi);
}

__global__ __launch_bounds__(256) void k4_inv(const float* __restrict__ Y,
                                              float* __restrict__ out) {
  __shared__ float2 tbl[256];
  __shared__ float2 Ys[256];
  __shared__ float G[256][36];  // [h][2*kx(+1)], 144B rows (16B aligned)
  const int tid = threadIdx.x;
  const int co = blockIdx.x;
  const int b = blockIdx.y;
  {
    float sv, cv;
    sincosf((float)tid * TWO_PI_256, &sv, &cv);
    tbl[tid] = make_float2(cv, sv);
  }
  Ys[tid] = *(const float2*)&Y[((long)(b * 32 + co) * 256 + tid) * 2];
  __syncthreads();
  {  // phase 1: thread = h; G[h][kx] = sum_ky Y[ky][kx] * e^{+i ky h th}
    float gr[16] = {}, gi[16] = {};
#pragma unroll 4
    for (int ky = 0; ky < 16; ++ky) {
      const float2 w = tbl[(ky * tid) & 255];
#pragma unroll
      for (int kx = 0; kx < 16; ++kx) {
        const float2 yv = Ys[ky * 16 + kx];
        gr[kx] += yv.x * w.x - yv.y * w.y;
        gi[kx] += yv.x * w.y + yv.y * w.x;
      }
    }
#pragma unroll
    for (int kx = 0; kx < 16; ++kx)
      *(float2*)&G[tid][2 * kx] = make_float2(gr[kx], gi[kx]);
  }
  __syncthreads();
  // phase 2: thread = (w-slot s, h-parity hh); fold w <-> 256-w
  const int s = tid & 127;
  const int hh = tid >> 7;
  float cs[16], sn[16];
#pragma unroll
  for (int kx = 1; kx < 16; ++kx) {
    const float2 w = tbl[(kx * s) & 255];
    cs[kx] = 2.f * w.x;
    sn[kx] = 2.f * w.y;
  }
  const float inv = 1.f / 65536.f;
  float* __restrict__ ob = out + (long)(b * 32 + co) * 65536;
  for (int h = hh; h < 256; h += 2) {
    float gr[16], gi[16];
#pragma unroll
    for (int j = 0; j < 8; ++j) {
      const v4 qv = *(const v4*)&G[h][4 * j];
      gr[2 * j] = qv[0];
      gi[2 * j] = qv[1];
      gr[2 * j + 1] = qv[2];
      gi[2 * j + 1] = qv[3];
    }
    float a = gr[0];
    float bs = 0.f;
#pragma unroll
    for (int kx = 1; kx < 16; ++kx) {
      a += gr[kx] * cs[kx];
      bs += gi[kx] * sn[kx];
    }
    if (s == 0) {
      // w=0 (a is correct) and w=128 (cos = (-1)^kx, sin = 0)
      float a128 = gr[0];
#pragma unroll
      for (int kx = 1; kx < 16; ++kx)
        a128 += (kx & 1) ? -2.f * gr[kx] : 2.f * gr[kx];
      ob[h * 256] = a * inv;
      ob[h * 256 + 128] = a128 * inv;
    } else {
      ob[h * 256 + s] = (a - bs) * inv;
      ob[h * 256 + 256 - s] = (a + bs) * inv;
    }
  }
}

extern "C" void kernel_launch(void* const* d_in, const int* in_sizes, int n_in,
                              void* d_out, int out_size, void* d_ws, size_t ws_size,
                              hipStream_t stream) {
  const float* x = (const float*)d_in[0];   // [16][32][256][256]
  const float* wt = (const float*)d_in[1];  // [32][32][16][16][2]
  float* out = (float*)d_out;               // [16][32][256][256]
  float* F = (float*)d_ws;                  // 131072*32 floats = 16.78 MB
  float* X = F + 4194304;                   // 512*256*2 floats = 1 MB
  float* Yv = X + 262144;                   // 512*256*2 floats = 1 MB
  unsigned short* Th = (unsigned short*)(Yv + 262144);  // 32*256 bf16 = 16 KB
  unsigned short* Tl = Th + 8192;                       // 32*256 bf16 = 16 KB
  k0_trig<<<1, 256, 0, stream>>>(Th, Tl);
  k1_dftw<<<1024, 256, 0, stream>>>(x, Th, Tl, F);
  k2_dfth<<<512, 256, 0, stream>>>(F, X);
  k3_mix<<<dim3(32, 16), 256, 0, stream>>>(X, wt, Yv);
  k4_inv<<<dim3(32, 16), 256, 0, stream>>>(Yv, out);
}